// Round 9
// baseline (128.449 us; speedup 1.0000x reference)
//
#include <hip/hip_runtime.h>

// EdgeSelectionRL: out[b,i,j] = sigmoid( sum_h relu(A[b,i,h] + Cc[b,j,h]) * w2[h] + b2 )
// A = xa·Wa^T + b1, Cc = xa·Wb^T.  B=8, C=256, F=128, H=256.
// R9 = R8 with the cvt_pkrtz type fix (bit_cast __fp16x2 -> _Float16x2).
// ONE node, no grid sync. Block = (b, 32-i-tile, 64-j-tile) computes its own
// A/Cc tiles via MFMA (6x redundant proj ~0.65us total, benign-duplicate global
// writes), __syncthreads, then R4's dot2 pairwise on self-written (L1-hot) tiles.
// Model: 15.1us base + 2.1/node + ~3.5us work.

typedef _Float16 h2 __attribute__((ext_vector_type(2)));
typedef _Float16 h8 __attribute__((ext_vector_type(8)));
typedef float    f4 __attribute__((ext_vector_type(4)));

constexpr int B  = 8;
constexpr int C  = 256;
constexpr int F  = 128;
constexpr int H  = 256;
constexpr int F2 = 2 * F;     // 256
constexpr int HOCT = H / 8;   // 32

#if __has_builtin(__builtin_amdgcn_fdot2)
__device__ __forceinline__ float fdot2(h2 a, h2 b, float c) {
    return __builtin_amdgcn_fdot2(a, b, c, false);
}
#else
__device__ __forceinline__ float fdot2(h2 a, h2 b, float c) {
    return c + (float)a.x * (float)b.x + (float)a.y * (float)b.y;
}
#endif

union HU { h8 v; h2 p[4]; };

__device__ __forceinline__ h2 pkrtz(float x, float y) {
    return __builtin_bit_cast(h2, __builtin_amdgcn_cvt_pkrtz(x, y));
}

__device__ __forceinline__ h8 cvt8(float4 a, float4 b) {
    HU u;
    u.p[0] = pkrtz(a.x, a.y);
    u.p[1] = pkrtz(a.z, a.w);
    u.p[2] = pkrtz(b.x, b.y);
    u.p[3] = pkrtz(b.z, b.w);
    return u.v;
}

__device__ __forceinline__ float4 ldg4(const float* p) {
    return *(const float4*)p;
}

// Grid 256 = b(8) x it(8) x jt(4). 512 threads = 8 waves.
// Phase A: 96 MFMA tiles (A: 2x16, Cc: 4x16 of h-tiles), 12 per wave, direct f32
//   loads + pkrtz cvt, D-layout (m89): lane l reg r -> row m0+(l>>4)*4+r, col h0+(l&15).
// Phase B: wave wv: hs=wv&3 (64-h slice), ih=wv>>2 (16-i half); lane = j offset.
__global__ __launch_bounds__(512) void fused(
    const float* __restrict__ xa, const float* __restrict__ W1,
    const float* __restrict__ b1, const float* __restrict__ w2,
    const float* __restrict__ b2p, float* __restrict__ out,
    _Float16* __restrict__ Ah, _Float16* __restrict__ CP8)
{
    __shared__ float red[3 * 32 * 64];   // 24 KB
    const int t   = threadIdx.x;
    const int blk = blockIdx.x;
    const int b   = blk >> 5;
    const int it  = (blk >> 2) & 7;
    const int jt  = blk & 3;
    const int i0  = it * 32;
    const int j0  = jt * 64;
    const int wv  = t >> 6;
    const int l   = t & 63;
    const int lm  = l & 15;
    const int lk  = (l >> 4) * 8;
    const int hs  = wv & 3;              // wave-uniform
    const int ih  = wv >> 2;             // wave-uniform

    // ---- w2 slice -> registers (overlaps phase A) ----
    h8 w2r[8];
    #pragma unroll
    for (int o = 0; o < 8; ++o) {
        const float* wq = w2 + (hs * 8 + o) * 8;
        w2r[o] = cvt8(ldg4(wq), ldg4(wq + 4));
    }

    // ---------------- Phase A: projection tiles ----------------
    #pragma unroll 1
    for (int T = wv * 12; T < wv * 12 + 12; ++T) {
        const bool ctype = T >= 32;          // wave-uniform branch
        const int Tt  = ctype ? T - 32 : T;
        const int mt  = Tt >> 4;
        const int ht  = Tt & 15;
        const int m0  = (ctype ? j0 : i0) + mt * 16;
        const int h0  = ht * 16;
        const float* xp = xa + (size_t)(b * C + m0 + lm) * F + lk;
        const float* wp = W1 + (size_t)(h0 + lm) * F2 + lk + (ctype ? F : 0);

        f4 acc = {0.f, 0.f, 0.f, 0.f};
        #pragma unroll
        for (int kk = 0; kk < 4; ++kk) {
            h8 af = cvt8(ldg4(xp + kk * 32), ldg4(xp + kk * 32 + 4));
            h8 wf = cvt8(ldg4(wp + kk * 32), ldg4(wp + kk * 32 + 4));
            acc = __builtin_amdgcn_mfma_f32_16x16x32_f16(af, wf, acc, 0, 0, 0);
        }

        const int h  = h0 + lm;
        const int mb = m0 + (l >> 4) * 4;
        if (!ctype) {
            const float bh = b1[h];
            #pragma unroll
            for (int r = 0; r < 4; ++r)
                Ah[(size_t)(b * C + mb + r) * H + h] = (_Float16)(acc[r] + bh);
        } else {
            #pragma unroll
            for (int r = 0; r < 4; ++r)   // mb+r is a global j row
                CP8[(((size_t)(b * HOCT + (h >> 3)) * C + (mb + r)) << 3) + (h & 7)]
                    = (_Float16)acc[r];
        }
    }

    __syncthreads();   // own-block writes visible (L1/L2); dup writes benign

    // ---------------- Phase B: dot2 pairwise ----------------
    const int j = j0 + l;
    float acc[16];
    #pragma unroll
    for (int ii = 0; ii < 16; ++ii) acc[ii] = 0.f;

    const _Float16* Ab  = Ah + (size_t)(b * C + i0 + ih * 16) * H + hs * 64;
    const _Float16* CPb = CP8 + (((size_t)(b * HOCT + hs * 8) * C + j) << 3);
    const h8 z = {0, 0, 0, 0, 0, 0, 0, 0};

    #pragma unroll 2
    for (int g = 0; g < 8; ++g) {
        h8 cc = *(const h8*)(CPb + ((size_t)g * C << 3));   // 16B/lane coalesced
        HU uw; uw.v = w2r[g];
        #pragma unroll
        for (int ii = 0; ii < 16; ++ii) {
            h8 ao = *(const h8*)(Ab + (size_t)ii * H + g * 8);  // wave-uniform
            h8 s  = __builtin_elementwise_max(ao + cc, z);      // pk_add+pk_max
            HU us; us.v = s;
            float a0 = acc[ii];
            a0 = fdot2(us.p[0], uw.p[0], a0);
            a0 = fdot2(us.p[1], uw.p[1], a0);
            a0 = fdot2(us.p[2], uw.p[2], a0);
            a0 = fdot2(us.p[3], uw.p[3], a0);
            acc[ii] = a0;
        }
    }

    if (hs > 0) {
        #pragma unroll
        for (int ii = 0; ii < 16; ++ii)
            red[((hs - 1) * 32 + ih * 16 + ii) * 64 + l] = acc[ii];
    }
    __syncthreads();
    if (hs == 0) {
        const float bb = b2p[0];
        #pragma unroll
        for (int ii = 0; ii < 16; ++ii) {
            const int row = ih * 16 + ii;
            float x = acc[ii]
                    + red[(0 * 32 + row) * 64 + l]
                    + red[(1 * 32 + row) * 64 + l]
                    + red[(2 * 32 + row) * 64 + l] + bb;
            out[(size_t)(b * C + i0 + row) * C + j] = 1.f / (1.f + __expf(-x));
        }
    }
}

extern "C" void kernel_launch(void* const* d_in, const int* in_sizes, int n_in,
                              void* d_out, int out_size, void* d_ws, size_t ws_size,
                              hipStream_t stream) {
    const float* xa = (const float*)d_in[0];
    const float* W1 = (const float*)d_in[1];
    const float* b1 = (const float*)d_in[2];
    const float* w2 = (const float*)d_in[3];
    const float* b2 = (const float*)d_in[4];
    float* out = (float*)d_out;

    _Float16* Ah  = (_Float16*)d_ws;                  // 1 MB
    _Float16* CP8 = Ah + (size_t)B * C * H;           // 1 MB

    fused<<<256, 512, 0, stream>>>(xa, W1, b1, w2, b2, out, Ah, CP8);
}

// Round 10
// 127.013 us; speedup vs baseline: 1.0113x; 1.0113x over previous
//
#include <hip/hip_runtime.h>

// EdgeSelectionRL: out[b,i,j] = sigmoid( sum_h relu(A[b,i,h] + Cc[b,j,h]) * w2[h] + b2 )
// A = xa·Wa^T + b1, Cc = xa·Wb^T.  B=8, C=256, F=128, H=256.
// R10 = R9 with PRIVATE per-block scratch slabs (48KB each, ws is ~256MB).
// R9's 128us: 256 blocks storing the same 2MB lines (4x/8x duplication across
// 8 XCDs) -> same-line store serialization + vmcnt(0) barrier drain. Private
// slabs remove all write sharing; Phase B reads dirty-hit own-XCD L2.
// Model: 15.1us base + 2.1/node + ~5us work -> 20.5-22.5us.

typedef _Float16 h2 __attribute__((ext_vector_type(2)));
typedef _Float16 h8 __attribute__((ext_vector_type(8)));
typedef float    f4 __attribute__((ext_vector_type(4)));

constexpr int B  = 8;
constexpr int C  = 256;
constexpr int F  = 128;
constexpr int H  = 256;
constexpr int F2 = 2 * F;     // 256

#if __has_builtin(__builtin_amdgcn_fdot2)
__device__ __forceinline__ float fdot2(h2 a, h2 b, float c) {
    return __builtin_amdgcn_fdot2(a, b, c, false);
}
#else
__device__ __forceinline__ float fdot2(h2 a, h2 b, float c) {
    return c + (float)a.x * (float)b.x + (float)a.y * (float)b.y;
}
#endif

union HU { h8 v; h2 p[4]; };

__device__ __forceinline__ h2 pkrtz(float x, float y) {
    return __builtin_bit_cast(h2, __builtin_amdgcn_cvt_pkrtz(x, y));
}

__device__ __forceinline__ h8 cvt8(float4 a, float4 b) {
    HU u;
    u.p[0] = pkrtz(a.x, a.y);
    u.p[1] = pkrtz(a.z, a.w);
    u.p[2] = pkrtz(b.x, b.y);
    u.p[3] = pkrtz(b.z, b.w);
    return u.v;
}

__device__ __forceinline__ float4 ldg4(const float* p) {
    return *(const float4*)p;
}

// Grid 256 = b(8) x it(8) x jt(4). 512 threads = 8 waves.
// Private slab per block: A 32x256 f16 (16KB) @ +0, Cc octet-packed (32KB) @ +8192.
// Phase A: 96 MFMA tiles (A: 32, Cc: 64), 12 per wave, direct f32 loads + pkrtz.
//   D layout (m89): lane l reg r -> row m0+(l>>4)*4+r, col h0+(l&15).
// Phase B: wave wv: hs=wv&3 (64-h slice), ih=wv>>2 (16-i half); lane = j offset.
__global__ __launch_bounds__(512) void fused(
    const float* __restrict__ xa, const float* __restrict__ W1,
    const float* __restrict__ b1, const float* __restrict__ w2,
    const float* __restrict__ b2p, float* __restrict__ out,
    _Float16* __restrict__ wsh)
{
    __shared__ float red[3 * 32 * 64];   // 24 KB
    const int t   = threadIdx.x;
    const int blk = blockIdx.x;
    const int b   = blk >> 5;
    const int it  = (blk >> 2) & 7;
    const int jt  = blk & 3;
    const int i0  = it * 32;
    const int j0  = jt * 64;
    const int wv  = t >> 6;
    const int l   = t & 63;
    const int lm  = l & 15;
    const int lk  = (l >> 4) * 8;
    const int hs  = wv & 3;              // wave-uniform
    const int ih  = wv >> 2;             // wave-uniform

    _Float16* __restrict__ Ap = wsh + (size_t)blk * 24576;   // 32*256
    _Float16* __restrict__ Cp = Ap + 32 * 256;               // 64*256 octet-packed

    // ---- w2 slice -> registers (overlaps phase A) ----
    h8 w2r[8];
    #pragma unroll
    for (int o = 0; o < 8; ++o) {
        const float* wq = w2 + (hs * 8 + o) * 8;
        w2r[o] = cvt8(ldg4(wq), ldg4(wq + 4));
    }

    // ---------------- Phase A: projection tiles (private writes) ----------
    #pragma unroll 2
    for (int T = wv * 12; T < wv * 12 + 12; ++T) {
        const bool ctype = T >= 32;          // wave-uniform branch
        const int Tt  = ctype ? T - 32 : T;
        const int mt  = Tt >> 4;             // A: 0..1, Cc: 0..3
        const int ht  = Tt & 15;
        const int m0L = mt * 16;                       // local row base
        const int m0G = (ctype ? j0 : i0) + m0L;       // global xa row
        const int h0  = ht * 16;
        const float* xp = xa + (size_t)(b * C + m0G + lm) * F + lk;
        const float* wp = W1 + (size_t)(h0 + lm) * F2 + lk + (ctype ? F : 0);

        f4 acc = {0.f, 0.f, 0.f, 0.f};
        #pragma unroll
        for (int kk = 0; kk < 4; ++kk) {
            h8 af = cvt8(ldg4(xp + kk * 32), ldg4(xp + kk * 32 + 4));
            h8 wf = cvt8(ldg4(wp + kk * 32), ldg4(wp + kk * 32 + 4));
            acc = __builtin_amdgcn_mfma_f32_16x16x32_f16(af, wf, acc, 0, 0, 0);
        }

        const int h   = h0 + lm;
        const int mbL = m0L + (l >> 4) * 4;
        if (!ctype) {
            const float bh = b1[h];
            #pragma unroll
            for (int r = 0; r < 4; ++r)
                Ap[(mbL + r) * H + h] = (_Float16)(acc[r] + bh);
        } else {
            #pragma unroll
            for (int r = 0; r < 4; ++r)   // local j row mbL+r, octet h>>3
                Cp[(((h >> 3) * 64 + mbL + r) << 3) + (h & 7)] = (_Float16)acc[r];
        }
    }

    __syncthreads();   // private writes drained to own-XCD L2

    // ---------------- Phase B: dot2 pairwise ----------------
    float acc[16];
    #pragma unroll
    for (int ii = 0; ii < 16; ++ii) acc[ii] = 0.f;

    const _Float16* Ab  = Ap + (ih * 16) * H + hs * 64;    // wave-uniform rows
    const _Float16* CPb = Cp + (((hs * 8) * 64 + l) << 3); // 16B/lane coalesced
    const h8 z = {0, 0, 0, 0, 0, 0, 0, 0};

    #pragma unroll 2
    for (int g = 0; g < 8; ++g) {
        h8 cc = *(const h8*)(CPb + ((size_t)g * 64 << 3));
        HU uw; uw.v = w2r[g];
        #pragma unroll
        for (int ii = 0; ii < 16; ++ii) {
            h8 ao = *(const h8*)(Ab + ii * H + g * 8);      // wave-uniform bcast
            h8 s  = __builtin_elementwise_max(ao + cc, z);  // pk_add+pk_max
            HU us; us.v = s;
            float a0 = acc[ii];
            a0 = fdot2(us.p[0], uw.p[0], a0);
            a0 = fdot2(us.p[1], uw.p[1], a0);
            a0 = fdot2(us.p[2], uw.p[2], a0);
            a0 = fdot2(us.p[3], uw.p[3], a0);
            acc[ii] = a0;
        }
    }

    if (hs > 0) {
        #pragma unroll
        for (int ii = 0; ii < 16; ++ii)
            red[((hs - 1) * 32 + ih * 16 + ii) * 64 + l] = acc[ii];
    }
    __syncthreads();
    if (hs == 0) {
        const float bb = b2p[0];
        #pragma unroll
        for (int ii = 0; ii < 16; ++ii) {
            const int row = ih * 16 + ii;
            float x = acc[ii]
                    + red[(0 * 32 + row) * 64 + l]
                    + red[(1 * 32 + row) * 64 + l]
                    + red[(2 * 32 + row) * 64 + l] + bb;
            out[(size_t)(b * C + i0 + row) * C + j0 + l] = 1.f / (1.f + __expf(-x));
        }
    }
}

extern "C" void kernel_launch(void* const* d_in, const int* in_sizes, int n_in,
                              void* d_out, int out_size, void* d_ws, size_t ws_size,
                              hipStream_t stream) {
    const float* xa = (const float*)d_in[0];
    const float* W1 = (const float*)d_in[1];
    const float* b1 = (const float*)d_in[2];
    const float* w2 = (const float*)d_in[3];
    const float* b2 = (const float*)d_in[4];
    float* out = (float*)d_out;

    _Float16* wsh = (_Float16*)d_ws;   // 256 blocks x 48KB private slabs = 12MB

    fused<<<256, 512, 0, stream>>>(xa, W1, b1, w2, b2, out, wsh);
}

// Round 11
// 23.551 us; speedup vs baseline: 5.4540x; 5.3931x over previous
//
#include <hip/hip_runtime.h>

// EdgeSelectionRL: out[b,i,j] = sigmoid( sum_h relu(A[b,i,h] + Cc[b,j,h]) * w2[h] + b2 )
// A = xa·Wa^T + b1, Cc = xa·Wb^T.  B=8, C=256, F=128, H=256.
// R11 = R4 (best, 23.8us) + k2 occupancy tweak: 512 blocks x 512 thr
// (j halved) -> 2 blocks/CU = 32 waves/CU for latency hiding; CP L2 traffic
// unchanged (each block reads its own j-half once). k1 verbatim.
// Session model: ~19.3us 2-node pedestal + device work (k1 ~0.7, k2 ~2.6-3.0).
// NOTE (R9/R10 lesson): never read back your own kernel's global stores --
// store->barrier->load within one dispatch stalled 128us with all pipes idle.

typedef _Float16 h2 __attribute__((ext_vector_type(2)));
typedef _Float16 h8 __attribute__((ext_vector_type(8)));
typedef float    f4 __attribute__((ext_vector_type(4)));

constexpr int B  = 8;
constexpr int C  = 256;
constexpr int F  = 128;
constexpr int H  = 256;
constexpr int F2 = 2 * F;     // 256
constexpr int HOCT = H / 8;   // 32

#if __has_builtin(__builtin_amdgcn_fdot2)
__device__ __forceinline__ float fdot2(h2 a, h2 b, float c) {
    return __builtin_amdgcn_fdot2(a, b, c, false);
}
#else
__device__ __forceinline__ float fdot2(h2 a, h2 b, float c) {
    return c + (float)a.x * (float)b.x + (float)a.y * (float)b.y;
}
#endif

union HU { h8 v; h2 p[4]; };

__device__ __forceinline__ h2 pkrtz(float x, float y) {
    return __builtin_bit_cast(h2, __builtin_amdgcn_cvt_pkrtz(x, y));
}

__device__ __forceinline__ h8 cvt8(float4 a, float4 b) {
    HU u;
    u.p[0] = pkrtz(a.x, a.y);
    u.p[1] = pkrtz(a.z, a.w);
    u.p[2] = pkrtz(b.x, b.y);
    u.p[3] = pkrtz(b.z, b.w);
    return u.v;
}

// ---------------- Kernel 1: fused cvt + projections via MFMA (R4 verbatim) --
// Wave w: 2 m-tiles at (w>>4)*32, h-tile (w&15)*16. Direct f32 global fragment
// loads, cvt in-register. D layout (m89): lane l, reg r -> row m0+(l>>4)*4+r,
// col h0+(l&15).
__global__ __launch_bounds__(256) void k1_mfma(
    const float* __restrict__ xa, const float* __restrict__ W1,
    const float* __restrict__ b1, const float* __restrict__ w2,
    _Float16* __restrict__ Ah, _Float16* __restrict__ CP8,
    _Float16* __restrict__ w2h)
{
    const int t  = threadIdx.x;
    const int w  = blockIdx.x * 4 + (t >> 6);   // 0..1023
    const int l  = t & 63;
    const int mg = w >> 4;                      // 0..63
    const int h0 = (w & 15) * 16;
    const int lm = l & 15;
    const int lk = (l >> 4) * 8;
    const int m0 = mg * 32;

    h8 af[2][4];
    const float* xp0 = xa + (size_t)(m0 + lm) * F + lk;
    const float* xp1 = xp0 + 16 * F;
    #pragma unroll
    for (int kk = 0; kk < 4; ++kk) {
        af[0][kk] = cvt8(*(const float4*)(xp0 + kk * 32),
                         *(const float4*)(xp0 + kk * 32 + 4));
        af[1][kk] = cvt8(*(const float4*)(xp1 + kk * 32),
                         *(const float4*)(xp1 + kk * 32 + 4));
    }

    const float* wp = W1 + (size_t)(h0 + lm) * F2 + lk;
    f4 accA0 = {0.f,0.f,0.f,0.f}, accA1 = {0.f,0.f,0.f,0.f};
    f4 accC0 = {0.f,0.f,0.f,0.f}, accC1 = {0.f,0.f,0.f,0.f};
    #pragma unroll
    for (int kk = 0; kk < 4; ++kk) {
        h8 ba = cvt8(*(const float4*)(wp + kk * 32),
                     *(const float4*)(wp + kk * 32 + 4));
        h8 bb = cvt8(*(const float4*)(wp + F + kk * 32),
                     *(const float4*)(wp + F + kk * 32 + 4));
        accA0 = __builtin_amdgcn_mfma_f32_16x16x32_f16(af[0][kk], ba, accA0, 0, 0, 0);
        accC0 = __builtin_amdgcn_mfma_f32_16x16x32_f16(af[0][kk], bb, accC0, 0, 0, 0);
        accA1 = __builtin_amdgcn_mfma_f32_16x16x32_f16(af[1][kk], ba, accA1, 0, 0, 0);
        accC1 = __builtin_amdgcn_mfma_f32_16x16x32_f16(af[1][kk], bb, accC1, 0, 0, 0);
    }

    const int h  = h0 + lm;
    const float bh = b1[h];
    #pragma unroll
    for (int mt = 0; mt < 2; ++mt) {
        const f4 aA = mt ? accA1 : accA0;
        const f4 aC = mt ? accC1 : accC0;
        const int mb = m0 + mt * 16 + (l >> 4) * 4;
        #pragma unroll
        for (int r = 0; r < 4; ++r) {
            const int m = mb + r;
            Ah[(size_t)m * H + h] = (_Float16)(aA[r] + bh);
            // h-octet-packed Cc: CP8[((b*HOCT+h/8)*C + i)*8 + (h&7)]
            CP8[(((size_t)((m >> 8) * HOCT + (h >> 3)) * C + (m & 255)) << 3) + (h & 7)]
                = (_Float16)aC[r];
        }
    }

    if (blockIdx.x == 0 && t < 128) {   // w2 -> fp16 once
        float2 wv = ((const float2*)w2)[t];
        h2 hv = {(_Float16)wv.x, (_Float16)wv.y};
        ((h2*)w2h)[t] = hv;
    }
}

// ---------------- Kernel 2: pairwise relu-dot + sigmoid --------------------
// Grid 512 = b(8) x it(32) x jh(2). Block 512 thr = 128 j x 4 h-splits
// (8 waves; 2 blocks/CU -> 32 waves/CU). TI=8 i-rows per block.
// A octets wave-uniform (L1 broadcast); cc octets 16B/lane coalesced; each
// block reads only its j-half of CP[b] (L2 traffic unchanged vs R4).
constexpr int TI = 8;
constexpr int HS = 4;
constexpr int JW = 128;   // j per block

__global__ __launch_bounds__(512) void k2_pair(
    const _Float16* __restrict__ Ah, const _Float16* __restrict__ CP8,
    const _Float16* __restrict__ w2h, const float* __restrict__ b2p,
    float* __restrict__ out)
{
    __shared__ float red[(HS - 1) * TI * JW];   // 12 KB
    const int t   = threadIdx.x;
    const int jl  = t & (JW - 1);
    const int hs  = t >> 7;                    // wave-uniform (2 waves per hs)
    const int blk = blockIdx.x;
    const int jh  = blk & 1;
    const int it  = (blk >> 1) & 31;
    const int b   = blk >> 6;
    const int i0  = it * TI;
    const int j   = jh * JW + jl;

    float acc[TI];
    #pragma unroll
    for (int ii = 0; ii < TI; ++ii) acc[ii] = 0.f;

    const int g0 = hs * (HOCT / HS);           // 8 octets per split
    const _Float16* Ab = Ah + (size_t)(b * C + i0) * H;

    #pragma unroll 2
    for (int g = 0; g < HOCT / HS; ++g) {
        const int hb = g0 + g;
        h8 cc = *(const h8*)(CP8 + (((size_t)(b * HOCT + hb) * C + j) << 3));
        HU uw; uw.v = *(const h8*)(w2h + hb * 8);         // uniform, L1
        #pragma unroll
        for (int ii = 0; ii < TI; ++ii) {
            h8 ao = *(const h8*)(Ab + ii * H + hb * 8);   // uniform -> bcast
            const h8 z = {0, 0, 0, 0, 0, 0, 0, 0};
            h8 s = __builtin_elementwise_max(ao + cc, z); // pk_add + pk_max
            HU us; us.v = s;
            float a0 = acc[ii];
            a0 = fdot2(us.p[0], uw.p[0], a0);             // v_dot2_f32_f16
            a0 = fdot2(us.p[1], uw.p[1], a0);
            a0 = fdot2(us.p[2], uw.p[2], a0);
            a0 = fdot2(us.p[3], uw.p[3], a0);
            acc[ii] = a0;
        }
    }

    if (hs > 0) {
        #pragma unroll
        for (int ii = 0; ii < TI; ++ii)
            red[((hs - 1) * TI + ii) * JW + jl] = acc[ii];
    }
    __syncthreads();
    if (hs == 0) {
        const float bb = b2p[0];
        #pragma unroll
        for (int ii = 0; ii < TI; ++ii) {
            float x = acc[ii]
                    + red[(0 * TI + ii) * JW + jl]
                    + red[(1 * TI + ii) * JW + jl]
                    + red[(2 * TI + ii) * JW + jl] + bb;
            out[(size_t)(b * C + i0 + ii) * C + j] = 1.f / (1.f + __expf(-x));
        }
    }
}

extern "C" void kernel_launch(void* const* d_in, const int* in_sizes, int n_in,
                              void* d_out, int out_size, void* d_ws, size_t ws_size,
                              hipStream_t stream) {
    const float* xa = (const float*)d_in[0];
    const float* W1 = (const float*)d_in[1];
    const float* b1 = (const float*)d_in[2];
    const float* w2 = (const float*)d_in[3];
    const float* b2 = (const float*)d_in[4];
    float* out = (float*)d_out;

    _Float16* Ah  = (_Float16*)d_ws;                  // 1 MB
    _Float16* CP8 = Ah  + (size_t)B * C * H;          // 1 MB
    _Float16* w2h = CP8 + (size_t)B * H * C;          // 512 B

    k1_mfma<<<256, 256, 0, stream>>>(xa, W1, b1, w2, Ah, CP8, w2h);
    k2_pair<<<512, 512, 0, stream>>>(Ah, CP8, w2h, b2, out);
}